// Round 5
// baseline (1142.578 us; speedup 1.0000x reference)
//
#include <hip/hip_runtime.h>
#include <hip/hip_bf16.h>

#define Nn 8
#define Cc 64
#define Tt 16
#define Hh 56
#define Ww 56

typedef __bf16 bf16x8 __attribute__((ext_vector_type(8)));
typedef float f32x4 __attribute__((ext_vector_type(4)));
typedef unsigned short u16;
typedef unsigned int u32;

// bit-exact RNE f32->bf16 (finite inputs only)
__device__ __forceinline__ u16 f32_to_bf16(float f) {
    u32 u = __float_as_uint(f);
    u32 r = (u + 0x7FFFu + ((u >> 16) & 1u)) >> 16;
    return (u16)r;
}
__device__ __forceinline__ float bf16_to_f32(u16 h) {
    return __uint_as_float(((u32)h) << 16);
}

// ---------------- P0: weights -> bf16 hi/lo in [tap][co][ci] ----------------
__global__ __launch_bounds__(256) void prep_w_kernel(
    const float* __restrict__ w1, const float* __restrict__ w2,
    u16* __restrict__ w1h, u16* __restrict__ w1l,
    u16* __restrict__ w2h, u16* __restrict__ w2l)
{
    int idx = blockIdx.x * 256 + threadIdx.x;      // 0 .. 221183
    int conv = idx / 110592;
    int rem  = idx % 110592;
    int tap  = rem >> 12;                           // /4096
    int co   = (rem >> 6) & 63;
    int ci   = rem & 63;
    const float* w = conv ? w2 : w1;
    float v = w[co * 1728 + ci * 27 + tap];
    u16 hi = f32_to_bf16(v);
    u16 lo = f32_to_bf16(v - bf16_to_f32(hi));
    int dst = tap * 4096 + co * 64 + ci;
    if (conv) { w2h[dst] = hi; w2l[dst] = lo; }
    else      { w1h[dst] = hi; w1l[dst] = lo; }
}

// ---------------- P1: x -> xh/xl bf16 in [n][t][h][w][ci] ----------------
__global__ __launch_bounds__(256) void split_x_kernel(
    const float* __restrict__ x, u16* __restrict__ xh, u16* __restrict__ xl)
{
    __shared__ float tile[Cc][Hh + 1];
    const int tid = threadIdx.x;
    const int bid = blockIdx.x;           // = (n*Tt + t)*Hh + h
    const int h = bid % Hh;
    const int t = (bid / Hh) % Tt;
    const int n = bid / (Hh * Tt);
    for (int it = 0; it < 14; ++it) {
        int id = it * 256 + tid;          // 3584 = 64ci * 56w
        int ci = id / Ww, w = id % Ww;
        tile[ci][w] = x[(((size_t)(n * Cc + ci) * Tt + t) * Hh + h) * Ww + w];
    }
    __syncthreads();
    const size_t obase = (size_t)bid * (Ww * Cc);
    for (int it = 0; it < 7; ++it) {
        int j = it * 256 + tid;           // 1792 ushort2 units
        int w = j >> 5, ci0 = (j & 31) << 1;
        float f0 = tile[ci0][w], f1 = tile[ci0 + 1][w];
        u16 h0 = f32_to_bf16(f0), h1 = f32_to_bf16(f1);
        u16 l0 = f32_to_bf16(f0 - bf16_to_f32(h0));
        u16 l1 = f32_to_bf16(f1 - bf16_to_f32(h1));
        size_t o = obase + (size_t)w * Cc + ci0;
        *(ushort2*)(xh + o) = make_ushort2(h0, h1);
        *(ushort2*)(xl + o) = make_ushort2(l0, l1);
    }
}

// ---------------- conv kernels ----------------
// LDS A slice: 58 rows (x-pos -1..56, rows 0 & 57 zero) x 32 ci halfwords = 64B/row.
// XOR swizzle: physical col16 = logical col16 ^ ((row>>1)&3)  (16B slots)
// A_PAD covers masked-lane frag reads up to row 65 (discarded in epilogue).
#define SLICE_B 3712                    // 58*64
#define A_PAD 512
#define A1_BYTES (10 * 2 * SLICE_B + A_PAD)   // 74752
#define A2_BYTES (10 * SLICE_B + A_PAD)       // 37632

__device__ __forceinline__ const bf16x8* frag_ptr(const char* base, int row, int g) {
    int col = (g * 16) ^ (((row >> 1) & 3) << 4);
    return (const bf16x8*)(base + row * 64 + col);
}
// B fragment direct from global: [tap][co][ci] layout, per-lane 16B
__device__ __forceinline__ bf16x8 ldB(const u16* __restrict__ w, int tap, int co, int cih, int g) {
    return *(const bf16x8*)(w + tap * 4096 + co * 64 + cih * 32 + g * 8);
}

__global__ __launch_bounds__(512, 4) void conv1_mfma_kernel(
    const u16* __restrict__ xh, const u16* __restrict__ xl,
    const u16* __restrict__ w1h, const u16* __restrict__ w1l,
    const float* __restrict__ b1, const float* __restrict__ e1,
    u16* __restrict__ res1)
{
    __shared__ __align__(16) char As[A1_BYTES];

    const int tid = threadIdx.x;
    const int l = tid & 63, wid = tid >> 6;
    const int g = l >> 4, r15 = l & 15;
    // XCD-chunked swizzle: 896 wgs = 8 XCDs x 112 contiguous
    const int bid = (blockIdx.x & 7) * 112 + (blockIdx.x >> 3);
    const int hb = bid % 7;
    const int t  = (bid / 7) % Tt;
    const int n  = bid / (7 * Tt);
    const int h0 = hb * 8;

    f32x4 acc[4][4] = {};

    for (int cih = 0; cih < 2; ++cih) {
      for (int kd = 0; kd < 3; ++kd) {
        const int td = t + kd - 1;
        if (td < 0 || td >= Tt) continue;          // block-uniform skip
        __syncthreads();                            // protect prev-iter reads
        // stage A: 20 units (10 slices x {hi,lo}), 58 rows x 4 slots, 4640 chunks
        {
          const size_t tdbase = (size_t)(n * Tt + td) * ((size_t)Hh * Ww * Cc);
          for (int it = 0; it < 10; ++it) {
            int fi = it * 512 + tid;
            if (fi < 4640) {
              int u = fi / 232;
              int c = fi % 232;
              int r = c >> 2, slot = c & 3;
              int s = u >> 1, half = u & 1;
              int hh = h0 - 1 + s;
              int sw = ((r >> 1) & 3) << 4;
              uint4 val = make_uint4(0, 0, 0, 0);
              if (hh >= 0 && hh < Hh && r >= 1 && r <= Ww) {
                const u16* src = (half ? xl : xh) + tdbase
                    + ((size_t)hh * Ww + (r - 1)) * Cc + cih * 32 + slot * 8;
                val = *(const uint4*)src;
              }
              *(uint4*)(As + u * SLICE_B + r * 64 + ((slot * 16) ^ sw)) = val;
            }
          }
        }
        __syncthreads();
        // compute: all kh,kw; B direct from global (L1/L2-resident)
        const char* Ab0 = As + (size_t)wid * 2 * SLICE_B;
#pragma unroll
        for (int kh = 0; kh < 3; ++kh) {
          const char* Ab = Ab0 + (size_t)kh * 2 * SLICE_B;
#pragma unroll
          for (int kw = 0; kw < 3; ++kw) {
            const int tap = (kd * 3 + kh) * 3 + kw;
            bf16x8 ah[4], al[4];
#pragma unroll
            for (int m = 0; m < 4; ++m) {
              int row = r15 + 16 * m + kw;
              ah[m] = *frag_ptr(Ab, row, g);
              al[m] = *frag_ptr(Ab + SLICE_B, row, g);
            }
            // nt in two halves to cap live B-frags (VGPR<=128)
#pragma unroll
            for (int np = 0; np < 2; ++np) {
              bf16x8 bh[2], bl[2];
#pragma unroll
              for (int q = 0; q < 2; ++q) {
                int co = r15 + 16 * (2 * np + q);
                bh[q] = ldB(w1h, tap, co, cih, g);
                bl[q] = ldB(w1l, tap, co, cih, g);
              }
#pragma unroll
              for (int m = 0; m < 4; ++m)
#pragma unroll
                for (int q = 0; q < 2; ++q) {
                  int nt = 2 * np + q;
                  acc[m][nt] = __builtin_amdgcn_mfma_f32_16x16x32_bf16(ah[m], bh[q], acc[m][nt], 0, 0, 0);
                  acc[m][nt] = __builtin_amdgcn_mfma_f32_16x16x32_bf16(al[m], bh[q], acc[m][nt], 0, 0, 0);
                  acc[m][nt] = __builtin_amdgcn_mfma_f32_16x16x32_bf16(ah[m], bl[q], acc[m][nt], 0, 0, 0);
                }
            }
          }
        }
      }
    }
    // epilogue: bias, BFP quant, relu, store bf16 (exact)
    const int h = h0 + wid;
    const size_t rowbase = ((size_t)(n * Tt + t) * Hh + h) * ((size_t)Ww * Cc);
#pragma unroll
    for (int nt = 0; nt < 4; ++nt) {
      int co = 16 * nt + r15;
      float e = e1[co];
      float sc = exp2f(7.0f - e), inv = exp2f(e - 7.0f);
      float bias = b1[co];
#pragma unroll
      for (int m = 0; m < 4; ++m)
#pragma unroll
        for (int j = 0; j < 4; ++j) {
          int w = 16 * m + 4 * g + j;
          if (w < Ww) {
            float v = acc[m][nt][j] + bias;
            float q = rintf(v * sc);
            q = fminf(fmaxf(q, -127.f), 127.f);
            v = fmaxf(q * inv, 0.0f);
            res1[rowbase + (size_t)w * Cc + co] = f32_to_bf16(v);
          }
        }
    }
}

__global__ __launch_bounds__(512, 4) void conv2_mfma_kernel(
    const u16* __restrict__ a, const u16* __restrict__ w2h, const u16* __restrict__ w2l,
    const float* __restrict__ b2, const float* __restrict__ e2,
    const float* __restrict__ x, float* __restrict__ out)
{
    __shared__ __align__(16) char As[A2_BYTES];

    const int tid = threadIdx.x;
    const int l = tid & 63, wid = tid >> 6;
    const int g = l >> 4, r15 = l & 15;
    const int bid = (blockIdx.x & 7) * 112 + (blockIdx.x >> 3);
    const int hb = bid % 7;
    const int t  = (bid / 7) % Tt;
    const int n  = bid / (7 * Tt);
    const int h0 = hb * 8;

    f32x4 acc[4][4] = {};

    for (int cih = 0; cih < 2; ++cih) {
      for (int kd = 0; kd < 3; ++kd) {
        const int td = t + kd - 1;
        if (td < 0 || td >= Tt) continue;
        __syncthreads();
        // stage A: 10 units x 232 chunks = 2320
        {
          const size_t tdbase = (size_t)(n * Tt + td) * ((size_t)Hh * Ww * Cc);
          for (int it = 0; it < 5; ++it) {
            int fi = it * 512 + tid;
            if (fi < 2320) {
              int u = fi / 232;
              int c = fi % 232;
              int r = c >> 2, slot = c & 3;
              int hh = h0 - 1 + u;
              int sw = ((r >> 1) & 3) << 4;
              uint4 val = make_uint4(0, 0, 0, 0);
              if (hh >= 0 && hh < Hh && r >= 1 && r <= Ww) {
                const u16* src = a + tdbase + ((size_t)hh * Ww + (r - 1)) * Cc + cih * 32 + slot * 8;
                val = *(const uint4*)src;
              }
              *(uint4*)(As + u * SLICE_B + r * 64 + ((slot * 16) ^ sw)) = val;
            }
          }
        }
        __syncthreads();
        const char* Ab0 = As + (size_t)wid * SLICE_B;
#pragma unroll
        for (int kh = 0; kh < 3; ++kh) {
          const char* Ab = Ab0 + (size_t)kh * SLICE_B;
#pragma unroll
          for (int kw = 0; kw < 3; ++kw) {
            const int tap = (kd * 3 + kh) * 3 + kw;
            bf16x8 af[4];
#pragma unroll
            for (int m = 0; m < 4; ++m) {
              int row = r15 + 16 * m + kw;
              af[m] = *frag_ptr(Ab, row, g);
            }
#pragma unroll
            for (int np = 0; np < 2; ++np) {
              bf16x8 bh[2], bl[2];
#pragma unroll
              for (int q = 0; q < 2; ++q) {
                int co = r15 + 16 * (2 * np + q);
                bh[q] = ldB(w2h, tap, co, cih, g);
                bl[q] = ldB(w2l, tap, co, cih, g);
              }
#pragma unroll
              for (int m = 0; m < 4; ++m)
#pragma unroll
                for (int q = 0; q < 2; ++q) {
                  int nt = 2 * np + q;
                  acc[m][nt] = __builtin_amdgcn_mfma_f32_16x16x32_bf16(af[m], bh[q], acc[m][nt], 0, 0, 0);
                  acc[m][nt] = __builtin_amdgcn_mfma_f32_16x16x32_bf16(af[m], bl[q], acc[m][nt], 0, 0, 0);
                }
            }
          }
        }
      }
    }
    // epilogue: conv-quant + identity-quant + relu -> f32 out (original NCDHW layout)
    const int h = h0 + wid;
#pragma unroll
    for (int nt = 0; nt < 4; ++nt) {
      int co = 16 * nt + r15;
      float e = e2[co];
      float sc = exp2f(7.0f - e), inv = exp2f(e - 7.0f);
      float bias = b2[co];
#pragma unroll
      for (int m = 0; m < 4; ++m)
#pragma unroll
        for (int j = 0; j < 4; ++j) {
          int w = 16 * m + 4 * g + j;
          if (w < Ww) {
            float v = acc[m][nt][j] + bias;
            float q = rintf(v * sc);
            q = fminf(fmaxf(q, -127.f), 127.f);
            v = q * inv;
            size_t xi = (((size_t)(n * Cc + co) * Tt + t) * Hh + h) * Ww + w;
            float xv = x[xi];
            float qx = rintf(xv * sc);
            qx = fminf(fmaxf(qx, -127.f), 127.f);
            out[xi] = fmaxf(qx * inv + v, 0.0f);
          }
        }
    }
}

extern "C" void kernel_launch(void* const* d_in, const int* in_sizes, int n_in,
                              void* d_out, int out_size, void* d_ws, size_t ws_size,
                              hipStream_t stream) {
    const float* x  = (const float*)d_in[0];
    const float* w1 = (const float*)d_in[1];
    const float* b1 = (const float*)d_in[2];
    const float* w2 = (const float*)d_in[3];
    const float* b2 = (const float*)d_in[4];
    const float* e1 = (const float*)d_in[5];
    const float* e2 = (const float*)d_in[6];

    // scratch layout
    const size_t NE = 25690112;            // out elems = 8*64*16*56*56
    u16* xh = (u16*)d_out;                 // d_out doubles as xh/xl scratch
    u16* xl = xh + NE;                     // exactly fills d_out (2*NE u16 = NE f32)
    char* ws = (char*)d_ws;
    u16* w1h = (u16*)(ws);
    u16* w1l = (u16*)(ws + 221184);
    u16* w2h = (u16*)(ws + 442368);
    u16* w2l = (u16*)(ws + 663552);
    u16* res1 = (u16*)(ws + 884736);       // 51.4 MB

    prep_w_kernel<<<864, 256, 0, stream>>>(w1, w2, w1h, w1l, w2h, w2l);
    split_x_kernel<<<Nn * Tt * Hh, 256, 0, stream>>>(x, xh, xl);
    const int nwg = Nn * Tt * 7;           // 896
    conv1_mfma_kernel<<<nwg, 512, 0, stream>>>(xh, xl, w1h, w1l, b1, e1, res1);
    conv2_mfma_kernel<<<nwg, 512, 0, stream>>>(res1, w2h, w2l, b2, e2, x, (float*)d_out);
}

// Round 6
// 926.224 us; speedup vs baseline: 1.2336x; 1.2336x over previous
//
#include <hip/hip_runtime.h>
#include <hip/hip_bf16.h>

#define Nn 8
#define Cc 64
#define Tt 16
#define Hh 56
#define Ww 56

typedef __bf16 bf16x8 __attribute__((ext_vector_type(8)));
typedef float f32x4 __attribute__((ext_vector_type(4)));
typedef unsigned short u16;
typedef unsigned int u32;

// bit-exact RNE f32->bf16 (finite inputs only)
__device__ __forceinline__ u16 f32_to_bf16(float f) {
    u32 u = __float_as_uint(f);
    u32 r = (u + 0x7FFFu + ((u >> 16) & 1u)) >> 16;
    return (u16)r;
}
__device__ __forceinline__ float bf16_to_f32(u16 h) {
    return __uint_as_float(((u32)h) << 16);
}

// ---------------- P0: weights -> bf16 hi/lo in [tap][co][ci] ----------------
__global__ __launch_bounds__(256) void prep_w_kernel(
    const float* __restrict__ w1, const float* __restrict__ w2,
    u16* __restrict__ w1h, u16* __restrict__ w1l,
    u16* __restrict__ w2h, u16* __restrict__ w2l)
{
    int idx = blockIdx.x * 256 + threadIdx.x;      // 0 .. 221183
    int conv = idx / 110592;
    int rem  = idx % 110592;
    int tap  = rem >> 12;                           // /4096
    int co   = (rem >> 6) & 63;
    int ci   = rem & 63;
    const float* w = conv ? w2 : w1;
    float v = w[co * 1728 + ci * 27 + tap];
    u16 hi = f32_to_bf16(v);
    u16 lo = f32_to_bf16(v - bf16_to_f32(hi));
    int dst = tap * 4096 + co * 64 + ci;
    if (conv) { w2h[dst] = hi; w2l[dst] = lo; }
    else      { w1h[dst] = hi; w1l[dst] = lo; }
}

// ---------------- P1: x -> xh/xl bf16 in [n][t][h][w][ci] ----------------
__global__ __launch_bounds__(256) void split_x_kernel(
    const float* __restrict__ x, u16* __restrict__ xh, u16* __restrict__ xl)
{
    __shared__ float tile[Cc][Hh + 1];
    const int tid = threadIdx.x;
    const int bid = blockIdx.x;           // = (n*Tt + t)*Hh + h
    const int h = bid % Hh;
    const int t = (bid / Hh) % Tt;
    const int n = bid / (Hh * Tt);
    for (int it = 0; it < 14; ++it) {
        int id = it * 256 + tid;          // 3584 = 64ci * 56w
        int ci = id / Ww, w = id % Ww;
        tile[ci][w] = x[(((size_t)(n * Cc + ci) * Tt + t) * Hh + h) * Ww + w];
    }
    __syncthreads();
    const size_t obase = (size_t)bid * (Ww * Cc);
    for (int it = 0; it < 7; ++it) {
        int j = it * 256 + tid;           // 1792 ushort2 units
        int w = j >> 5, ci0 = (j & 31) << 1;
        float f0 = tile[ci0][w], f1 = tile[ci0 + 1][w];
        u16 h0 = f32_to_bf16(f0), h1 = f32_to_bf16(f1);
        u16 l0 = f32_to_bf16(f0 - bf16_to_f32(h0));
        u16 l1 = f32_to_bf16(f1 - bf16_to_f32(h1));
        size_t o = obase + (size_t)w * Cc + ci0;
        *(ushort2*)(xh + o) = make_ushort2(h0, h1);
        *(ushort2*)(xl + o) = make_ushort2(l0, l1);
    }
}

// ---------------- conv kernels ----------------
// LDS A slice: 58 rows (x-pos -1..56, rows 0 & 57 zero) x 32 ci halfwords = 64B/row.
// XOR swizzle: physical col16 = logical col16 ^ ((row>>1)&3)  (16B slots)
// A_PAD covers masked-lane frag reads up to row 65 (discarded in epilogue).
#define SLICE_B 3712                    // 58*64
#define A_PAD 512
#define A1_BYTES (10 * 2 * SLICE_B + A_PAD)   // 74752
#define A2_BYTES (10 * SLICE_B + A_PAD)       // 37632

__device__ __forceinline__ const bf16x8* frag_ptr(const char* base, int row, int g) {
    int col = (g * 16) ^ (((row >> 1) & 3) << 4);
    return (const bf16x8*)(base + row * 64 + col);
}
// B fragment direct from global: [tap][co][ci] layout, per-lane 16B
__device__ __forceinline__ bf16x8 ldB(const u16* __restrict__ w, int tap, int co, int cih, int g) {
    return *(const bf16x8*)(w + tap * 4096 + co * 64 + cih * 32 + g * 8);
}

__global__ __launch_bounds__(512, 2) void conv1_mfma_kernel(
    const u16* __restrict__ xh, const u16* __restrict__ xl,
    const u16* __restrict__ w1h, const u16* __restrict__ w1l,
    const float* __restrict__ b1, const float* __restrict__ e1,
    u16* __restrict__ res1)
{
    __shared__ __align__(16) char As[A1_BYTES];

    const int tid = threadIdx.x;
    const int l = tid & 63, wid = tid >> 6;
    const int g = l >> 4, r15 = l & 15;
    // XCD-chunked swizzle: 896 wgs = 8 XCDs x 112 contiguous
    const int bid = (blockIdx.x & 7) * 112 + (blockIdx.x >> 3);
    const int hb = bid % 7;
    const int t  = (bid / 7) % Tt;
    const int n  = bid / (7 * Tt);
    const int h0 = hb * 8;

    f32x4 acc[4][4] = {};

    for (int cih = 0; cih < 2; ++cih) {
      for (int kd = 0; kd < 3; ++kd) {
        const int td = t + kd - 1;
        if (td < 0 || td >= Tt) continue;          // block-uniform skip
        __syncthreads();                            // protect prev-iter reads
        // stage A: 20 units (10 slices x {hi,lo}), 58 rows x 4 slots, 4640 chunks
        {
          const size_t tdbase = (size_t)(n * Tt + td) * ((size_t)Hh * Ww * Cc);
          for (int it = 0; it < 10; ++it) {
            int fi = it * 512 + tid;
            if (fi < 4640) {
              int u = fi / 232;
              int c = fi % 232;
              int r = c >> 2, slot = c & 3;
              int s = u >> 1, half = u & 1;
              int hh = h0 - 1 + s;
              int sw = ((r >> 1) & 3) << 4;
              uint4 val = make_uint4(0, 0, 0, 0);
              if (hh >= 0 && hh < Hh && r >= 1 && r <= Ww) {
                const u16* src = (half ? xl : xh) + tdbase
                    + ((size_t)hh * Ww + (r - 1)) * Cc + cih * 32 + slot * 8;
                val = *(const uint4*)src;
              }
              *(uint4*)(As + u * SLICE_B + r * 64 + ((slot * 16) ^ sw)) = val;
            }
          }
        }
        __syncthreads();
        // compute: all kh,kw; B direct from global (L1/L2-resident)
        const char* Ab0 = As + (size_t)wid * 2 * SLICE_B;
#pragma unroll
        for (int kh = 0; kh < 3; ++kh) {
          const char* Ab = Ab0 + (size_t)kh * 2 * SLICE_B;
#pragma unroll
          for (int kw = 0; kw < 3; ++kw) {
            const int tap = (kd * 3 + kh) * 3 + kw;
            bf16x8 ah[4], al[4];
#pragma unroll
            for (int m = 0; m < 4; ++m) {
              int row = r15 + 16 * m + kw;
              ah[m] = *frag_ptr(Ab, row, g);
              al[m] = *frag_ptr(Ab + SLICE_B, row, g);
            }
            // nt in two halves to cap live B-frags
#pragma unroll
            for (int np = 0; np < 2; ++np) {
              bf16x8 bh[2], bl[2];
#pragma unroll
              for (int q = 0; q < 2; ++q) {
                int co = r15 + 16 * (2 * np + q);
                bh[q] = ldB(w1h, tap, co, cih, g);
                bl[q] = ldB(w1l, tap, co, cih, g);
              }
#pragma unroll
              for (int m = 0; m < 4; ++m)
#pragma unroll
                for (int q = 0; q < 2; ++q) {
                  int nt = 2 * np + q;
                  acc[m][nt] = __builtin_amdgcn_mfma_f32_16x16x32_bf16(ah[m], bh[q], acc[m][nt], 0, 0, 0);
                  acc[m][nt] = __builtin_amdgcn_mfma_f32_16x16x32_bf16(al[m], bh[q], acc[m][nt], 0, 0, 0);
                  acc[m][nt] = __builtin_amdgcn_mfma_f32_16x16x32_bf16(ah[m], bl[q], acc[m][nt], 0, 0, 0);
                }
            }
          }
        }
      }
    }
    // epilogue: bias, BFP quant, relu, store bf16 (exact)
    const int h = h0 + wid;
    const size_t rowbase = ((size_t)(n * Tt + t) * Hh + h) * ((size_t)Ww * Cc);
#pragma unroll
    for (int nt = 0; nt < 4; ++nt) {
      int co = 16 * nt + r15;
      float e = e1[co];
      float sc = exp2f(7.0f - e), inv = exp2f(e - 7.0f);
      float bias = b1[co];
#pragma unroll
      for (int m = 0; m < 4; ++m)
#pragma unroll
        for (int j = 0; j < 4; ++j) {
          int w = 16 * m + 4 * g + j;
          if (w < Ww) {
            float v = acc[m][nt][j] + bias;
            float q = rintf(v * sc);
            q = fminf(fmaxf(q, -127.f), 127.f);
            v = fmaxf(q * inv, 0.0f);
            res1[rowbase + (size_t)w * Cc + co] = f32_to_bf16(v);
          }
        }
    }
}

__global__ __launch_bounds__(512, 2) void conv2_mfma_kernel(
    const u16* __restrict__ a, const u16* __restrict__ w2h, const u16* __restrict__ w2l,
    const float* __restrict__ b2, const float* __restrict__ e2,
    const float* __restrict__ x, float* __restrict__ out)
{
    __shared__ __align__(16) char As[A2_BYTES];

    const int tid = threadIdx.x;
    const int l = tid & 63, wid = tid >> 6;
    const int g = l >> 4, r15 = l & 15;
    const int bid = (blockIdx.x & 7) * 112 + (blockIdx.x >> 3);
    const int hb = bid % 7;
    const int t  = (bid / 7) % Tt;
    const int n  = bid / (7 * Tt);
    const int h0 = hb * 8;

    f32x4 acc[4][4] = {};

    for (int cih = 0; cih < 2; ++cih) {
      for (int kd = 0; kd < 3; ++kd) {
        const int td = t + kd - 1;
        if (td < 0 || td >= Tt) continue;
        __syncthreads();
        // stage A: 10 units x 232 chunks = 2320
        {
          const size_t tdbase = (size_t)(n * Tt + td) * ((size_t)Hh * Ww * Cc);
          for (int it = 0; it < 5; ++it) {
            int fi = it * 512 + tid;
            if (fi < 2320) {
              int u = fi / 232;
              int c = fi % 232;
              int r = c >> 2, slot = c & 3;
              int hh = h0 - 1 + u;
              int sw = ((r >> 1) & 3) << 4;
              uint4 val = make_uint4(0, 0, 0, 0);
              if (hh >= 0 && hh < Hh && r >= 1 && r <= Ww) {
                const u16* src = a + tdbase + ((size_t)hh * Ww + (r - 1)) * Cc + cih * 32 + slot * 8;
                val = *(const uint4*)src;
              }
              *(uint4*)(As + u * SLICE_B + r * 64 + ((slot * 16) ^ sw)) = val;
            }
          }
        }
        __syncthreads();
        const char* Ab0 = As + (size_t)wid * SLICE_B;
#pragma unroll
        for (int kh = 0; kh < 3; ++kh) {
          const char* Ab = Ab0 + (size_t)kh * SLICE_B;
#pragma unroll
          for (int kw = 0; kw < 3; ++kw) {
            const int tap = (kd * 3 + kh) * 3 + kw;
            bf16x8 af[4];
#pragma unroll
            for (int m = 0; m < 4; ++m) {
              int row = r15 + 16 * m + kw;
              af[m] = *frag_ptr(Ab, row, g);
            }
#pragma unroll
            for (int np = 0; np < 2; ++np) {
              bf16x8 bh[2], bl[2];
#pragma unroll
              for (int q = 0; q < 2; ++q) {
                int co = r15 + 16 * (2 * np + q);
                bh[q] = ldB(w2h, tap, co, cih, g);
                bl[q] = ldB(w2l, tap, co, cih, g);
              }
#pragma unroll
              for (int m = 0; m < 4; ++m)
#pragma unroll
                for (int q = 0; q < 2; ++q) {
                  int nt = 2 * np + q;
                  acc[m][nt] = __builtin_amdgcn_mfma_f32_16x16x32_bf16(af[m], bh[q], acc[m][nt], 0, 0, 0);
                  acc[m][nt] = __builtin_amdgcn_mfma_f32_16x16x32_bf16(af[m], bl[q], acc[m][nt], 0, 0, 0);
                }
            }
          }
        }
      }
    }
    // epilogue: conv-quant + identity-quant + relu -> f32 out (original NCDHW layout)
    const int h = h0 + wid;
#pragma unroll
    for (int nt = 0; nt < 4; ++nt) {
      int co = 16 * nt + r15;
      float e = e2[co];
      float sc = exp2f(7.0f - e), inv = exp2f(e - 7.0f);
      float bias = b2[co];
#pragma unroll
      for (int m = 0; m < 4; ++m)
#pragma unroll
        for (int j = 0; j < 4; ++j) {
          int w = 16 * m + 4 * g + j;
          if (w < Ww) {
            float v = acc[m][nt][j] + bias;
            float q = rintf(v * sc);
            q = fminf(fmaxf(q, -127.f), 127.f);
            v = q * inv;
            size_t xi = (((size_t)(n * Cc + co) * Tt + t) * Hh + h) * Ww + w;
            float xv = x[xi];
            float qx = rintf(xv * sc);
            qx = fminf(fmaxf(qx, -127.f), 127.f);
            out[xi] = fmaxf(qx * inv + v, 0.0f);
          }
        }
    }
}

extern "C" void kernel_launch(void* const* d_in, const int* in_sizes, int n_in,
                              void* d_out, int out_size, void* d_ws, size_t ws_size,
                              hipStream_t stream) {
    const float* x  = (const float*)d_in[0];
    const float* w1 = (const float*)d_in[1];
    const float* b1 = (const float*)d_in[2];
    const float* w2 = (const float*)d_in[3];
    const float* b2 = (const float*)d_in[4];
    const float* e1 = (const float*)d_in[5];
    const float* e2 = (const float*)d_in[6];

    // scratch layout
    const size_t NE = 25690112;            // out elems = 8*64*16*56*56
    u16* xh = (u16*)d_out;                 // d_out doubles as xh/xl scratch
    u16* xl = xh + NE;                     // exactly fills d_out (2*NE u16 = NE f32)
    char* ws = (char*)d_ws;
    u16* w1h = (u16*)(ws);
    u16* w1l = (u16*)(ws + 221184);
    u16* w2h = (u16*)(ws + 442368);
    u16* w2l = (u16*)(ws + 663552);
    u16* res1 = (u16*)(ws + 884736);       // 51.4 MB

    prep_w_kernel<<<864, 256, 0, stream>>>(w1, w2, w1h, w1l, w2h, w2l);
    split_x_kernel<<<Nn * Tt * Hh, 256, 0, stream>>>(x, xh, xl);
    const int nwg = Nn * Tt * 7;           // 896
    conv1_mfma_kernel<<<nwg, 512, 0, stream>>>(xh, xl, w1h, w1l, b1, e1, res1);
    conv2_mfma_kernel<<<nwg, 512, 0, stream>>>(res1, w2h, w2l, b2, e2, x, (float*)d_out);
}

// Round 7
// 469.839 us; speedup vs baseline: 2.4319x; 1.9714x over previous
//
#include <hip/hip_runtime.h>
#include <hip/hip_bf16.h>

#define Nn 8
#define Cc 64
#define Tt 16
#define Hh 56
#define Ww 56

typedef __bf16 bf16x8 __attribute__((ext_vector_type(8)));
typedef float f32x4 __attribute__((ext_vector_type(4)));
typedef unsigned short u16;
typedef unsigned int u32;

// bit-exact RNE f32->bf16 (finite inputs only)
__device__ __forceinline__ u16 f32_to_bf16(float f) {
    u32 u = __float_as_uint(f);
    u32 r = (u + 0x7FFFu + ((u >> 16) & 1u)) >> 16;
    return (u16)r;
}
__device__ __forceinline__ float bf16_to_f32(u16 h) {
    return __uint_as_float(((u32)h) << 16);
}

// ---------------- P0: weights -> bf16 hi/lo in [tap][co][ci] ----------------
__global__ __launch_bounds__(256) void prep_w_kernel(
    const float* __restrict__ w1, const float* __restrict__ w2,
    u16* __restrict__ w1h, u16* __restrict__ w1l,
    u16* __restrict__ w2h, u16* __restrict__ w2l)
{
    int idx = blockIdx.x * 256 + threadIdx.x;      // 0 .. 221183
    int conv = idx / 110592;
    int rem  = idx % 110592;
    int tap  = rem >> 12;                           // /4096
    int co   = (rem >> 6) & 63;
    int ci   = rem & 63;
    const float* w = conv ? w2 : w1;
    float v = w[co * 1728 + ci * 27 + tap];
    u16 hi = f32_to_bf16(v);
    u16 lo = f32_to_bf16(v - bf16_to_f32(hi));
    int dst = tap * 4096 + co * 64 + ci;
    if (conv) { w2h[dst] = hi; w2l[dst] = lo; }
    else      { w1h[dst] = hi; w1l[dst] = lo; }
}

// ---------------- P1: x -> xh/xl bf16 in [n][t][h][w][ci] ----------------
__global__ __launch_bounds__(256) void split_x_kernel(
    const float* __restrict__ x, u16* __restrict__ xh, u16* __restrict__ xl)
{
    __shared__ float tile[Cc][Hh + 1];
    const int tid = threadIdx.x;
    const int bid = blockIdx.x;           // = (n*Tt + t)*Hh + h
    const int h = bid % Hh;
    const int t = (bid / Hh) % Tt;
    const int n = bid / (Hh * Tt);
    for (int it = 0; it < 14; ++it) {
        int id = it * 256 + tid;          // 3584 = 64ci * 56w
        int ci = id / Ww, w = id % Ww;
        tile[ci][w] = x[(((size_t)(n * Cc + ci) * Tt + t) * Hh + h) * Ww + w];
    }
    __syncthreads();
    const size_t obase = (size_t)bid * (Ww * Cc);
    for (int it = 0; it < 7; ++it) {
        int j = it * 256 + tid;           // 1792 ushort2 units
        int w = j >> 5, ci0 = (j & 31) << 1;
        float f0 = tile[ci0][w], f1 = tile[ci0 + 1][w];
        u16 h0 = f32_to_bf16(f0), h1 = f32_to_bf16(f1);
        u16 l0 = f32_to_bf16(f0 - bf16_to_f32(h0));
        u16 l1 = f32_to_bf16(f1 - bf16_to_f32(h1));
        size_t o = obase + (size_t)w * Cc + ci0;
        *(ushort2*)(xh + o) = make_ushort2(h0, h1);
        *(ushort2*)(xl + o) = make_ushort2(l0, l1);
    }
}

// ---------------- conv kernels ----------------
// LDS A slice: 58 rows (x-pos -1..56, rows 0 & 57 zero) x 32 ci halfwords = 64B/row.
// XOR swizzle: physical col16 = logical col16 ^ ((row>>1)&3)  (16B slots)
// A pad (+512) covers masked-lane frag reads up to row 65 (discarded in epilogue).
#define SLICE_B 3712                        // 58*64
#define A1_REG (10 * 2 * SLICE_B + 512)     // 74752
#define A2_REG (10 * SLICE_B + 512)         // 37632
#define B_REG  (2 * 9 * 4096)               // 73728  (hi/lo x 9 taps x 64co x 32ci)

__device__ __forceinline__ const bf16x8* frag_ptr(const char* base, int row, int g) {
    int col = (g * 16) ^ (((row >> 1) & 3) << 4);
    return (const bf16x8*)(base + row * 64 + col);
}

__global__ __launch_bounds__(512, 2) void conv1_mfma_kernel(
    const u16* __restrict__ xh, const u16* __restrict__ xl,
    const u16* __restrict__ w1h, const u16* __restrict__ w1l,
    const float* __restrict__ b1, const float* __restrict__ e1,
    u16* __restrict__ res1)
{
    __shared__ __align__(16) char smem[A1_REG + B_REG];   // 148480 B
    char* As = smem;
    char* Bs = smem + A1_REG;

    const int tid = threadIdx.x;
    const int l = tid & 63, wid = tid >> 6;
    const int g = l >> 4, r15 = l & 15;
    // XCD-chunked swizzle: 896 wgs = 8 XCDs x 112 contiguous
    const int bid = (blockIdx.x & 7) * 112 + (blockIdx.x >> 3);
    const int hb = bid % 7;
    const int t  = (bid / 7) % Tt;
    const int n  = bid / (7 * Tt);
    const int h0 = hb * 8;

    f32x4 acc[4][4] = {};

    for (int cih = 0; cih < 2; ++cih) {
      for (int kd = 0; kd < 3; ++kd) {
        const int td = t + kd - 1;
        if (td < 0 || td >= Tt) continue;          // block-uniform skip
        __syncthreads();                            // protect prev slab reads
        // stage A: 20 units (10 slices x {hi,lo}) x 58 rows x 4 slots = 4640 chunks
        {
          const size_t tdbase = (size_t)(n * Tt + td) * ((size_t)Hh * Ww * Cc);
          for (int it = 0; it < 10; ++it) {
            int fi = it * 512 + tid;
            if (fi < 4640) {
              int u = fi / 232;
              int c = fi % 232;
              int r = c >> 2, slot = c & 3;
              int s = u >> 1, half = u & 1;
              int hh = h0 - 1 + s;
              int sw = ((r >> 1) & 3) << 4;
              uint4 val = make_uint4(0, 0, 0, 0);
              if (hh >= 0 && hh < Hh && r >= 1 && r <= Ww) {
                const u16* src = (half ? xl : xh) + tdbase
                    + ((size_t)hh * Ww + (r - 1)) * Cc + cih * 32 + slot * 8;
                val = *(const uint4*)src;
              }
              *(uint4*)(As + u * SLICE_B + r * 64 + ((slot * 16) ^ sw)) = val;
            }
          }
        }
        // stage B: all 9 taps of this kd, hi+lo: 18 units x 64co x 4 slots = 4608 chunks
        {
          int fi = tid;
          for (int it = 0; it < 9; ++it, fi += 512) {
            int u = fi >> 8;                 // 0..17 = hl*9 + tap9
            int c = fi & 255;
            int co = c >> 2, slot = c & 3;
            int hl = u / 9, tap9 = u % 9;
            const u16* src = (hl ? w1l : w1h)
                + (kd * 9 + tap9) * 4096 + co * 64 + cih * 32 + slot * 8;
            int sw = ((co >> 1) & 3) << 4;
            *(uint4*)(Bs + u * 4096 + co * 64 + ((slot * 16) ^ sw)) = *(const uint4*)src;
          }
        }
        __syncthreads();
        // compute: one long phase, 9 taps x 48 MFMA per wave
        const char* Ab0 = As + (size_t)wid * 2 * SLICE_B;
#pragma unroll
        for (int kh = 0; kh < 3; ++kh) {
          const char* Ab = Ab0 + (size_t)kh * 2 * SLICE_B;
#pragma unroll
          for (int kw = 0; kw < 3; ++kw) {
            const int tap9 = kh * 3 + kw;
            bf16x8 ah[4], al[4], bh[4], bl[4];
#pragma unroll
            for (int m = 0; m < 4; ++m) {
              int row = r15 + 16 * m + kw;
              ah[m] = *frag_ptr(Ab, row, g);
              al[m] = *frag_ptr(Ab + SLICE_B, row, g);
            }
#pragma unroll
            for (int nt = 0; nt < 4; ++nt) {
              int co = r15 + 16 * nt;
              bh[nt] = *frag_ptr(Bs + tap9 * 4096, co, g);
              bl[nt] = *frag_ptr(Bs + (9 + tap9) * 4096, co, g);
            }
#pragma unroll
            for (int m = 0; m < 4; ++m)
#pragma unroll
              for (int nt = 0; nt < 4; ++nt) {
                acc[m][nt] = __builtin_amdgcn_mfma_f32_16x16x32_bf16(ah[m], bh[nt], acc[m][nt], 0, 0, 0);
                acc[m][nt] = __builtin_amdgcn_mfma_f32_16x16x32_bf16(al[m], bh[nt], acc[m][nt], 0, 0, 0);
                acc[m][nt] = __builtin_amdgcn_mfma_f32_16x16x32_bf16(ah[m], bl[nt], acc[m][nt], 0, 0, 0);
              }
          }
        }
      }
    }
    // epilogue: bias, BFP quant, relu, store bf16 (exact)
    const int h = h0 + wid;
    const size_t rowbase = ((size_t)(n * Tt + t) * Hh + h) * ((size_t)Ww * Cc);
#pragma unroll
    for (int nt = 0; nt < 4; ++nt) {
      int co = 16 * nt + r15;
      float e = e1[co];
      float sc = exp2f(7.0f - e), inv = exp2f(e - 7.0f);
      float bias = b1[co];
#pragma unroll
      for (int m = 0; m < 4; ++m)
#pragma unroll
        for (int j = 0; j < 4; ++j) {
          int w = 16 * m + 4 * g + j;
          if (w < Ww) {
            float v = acc[m][nt][j] + bias;
            float q = rintf(v * sc);
            q = fminf(fmaxf(q, -127.f), 127.f);
            v = fmaxf(q * inv, 0.0f);
            res1[rowbase + (size_t)w * Cc + co] = f32_to_bf16(v);
          }
        }
    }
}

__global__ __launch_bounds__(512, 2) void conv2_mfma_kernel(
    const u16* __restrict__ a, const u16* __restrict__ w2h, const u16* __restrict__ w2l,
    const float* __restrict__ b2, const float* __restrict__ e2,
    const float* __restrict__ x, float* __restrict__ out)
{
    __shared__ __align__(16) char smem[A2_REG + B_REG];   // 111360 B
    char* As = smem;
    char* Bs = smem + A2_REG;

    const int tid = threadIdx.x;
    const int l = tid & 63, wid = tid >> 6;
    const int g = l >> 4, r15 = l & 15;
    const int bid = (blockIdx.x & 7) * 112 + (blockIdx.x >> 3);
    const int hb = bid % 7;
    const int t  = (bid / 7) % Tt;
    const int n  = bid / (7 * Tt);
    const int h0 = hb * 8;

    f32x4 acc[4][4] = {};

    for (int cih = 0; cih < 2; ++cih) {
      for (int kd = 0; kd < 3; ++kd) {
        const int td = t + kd - 1;
        if (td < 0 || td >= Tt) continue;
        __syncthreads();
        // stage A: 10 units x 58 rows x 4 slots = 2320 chunks
        {
          const size_t tdbase = (size_t)(n * Tt + td) * ((size_t)Hh * Ww * Cc);
          for (int it = 0; it < 5; ++it) {
            int fi = it * 512 + tid;
            if (fi < 2320) {
              int u = fi / 232;
              int c = fi % 232;
              int r = c >> 2, slot = c & 3;
              int hh = h0 - 1 + u;
              int sw = ((r >> 1) & 3) << 4;
              uint4 val = make_uint4(0, 0, 0, 0);
              if (hh >= 0 && hh < Hh && r >= 1 && r <= Ww) {
                const u16* src = a + tdbase + ((size_t)hh * Ww + (r - 1)) * Cc + cih * 32 + slot * 8;
                val = *(const uint4*)src;
              }
              *(uint4*)(As + u * SLICE_B + r * 64 + ((slot * 16) ^ sw)) = val;
            }
          }
        }
        // stage B: 18 units x 64co x 4 slots = 4608 chunks
        {
          int fi = tid;
          for (int it = 0; it < 9; ++it, fi += 512) {
            int u = fi >> 8;
            int c = fi & 255;
            int co = c >> 2, slot = c & 3;
            int hl = u / 9, tap9 = u % 9;
            const u16* src = (hl ? w2l : w2h)
                + (kd * 9 + tap9) * 4096 + co * 64 + cih * 32 + slot * 8;
            int sw = ((co >> 1) & 3) << 4;
            *(uint4*)(Bs + u * 4096 + co * 64 + ((slot * 16) ^ sw)) = *(const uint4*)src;
          }
        }
        __syncthreads();
        const char* Ab0 = As + (size_t)wid * SLICE_B;
#pragma unroll
        for (int kh = 0; kh < 3; ++kh) {
          const char* Ab = Ab0 + (size_t)kh * SLICE_B;
#pragma unroll
          for (int kw = 0; kw < 3; ++kw) {
            const int tap9 = kh * 3 + kw;
            bf16x8 af[4], bh[4], bl[4];
#pragma unroll
            for (int m = 0; m < 4; ++m) {
              int row = r15 + 16 * m + kw;
              af[m] = *frag_ptr(Ab, row, g);
            }
#pragma unroll
            for (int nt = 0; nt < 4; ++nt) {
              int co = r15 + 16 * nt;
              bh[nt] = *frag_ptr(Bs + tap9 * 4096, co, g);
              bl[nt] = *frag_ptr(Bs + (9 + tap9) * 4096, co, g);
            }
#pragma unroll
            for (int m = 0; m < 4; ++m)
#pragma unroll
              for (int nt = 0; nt < 4; ++nt) {
                acc[m][nt] = __builtin_amdgcn_mfma_f32_16x16x32_bf16(af[m], bh[nt], acc[m][nt], 0, 0, 0);
                acc[m][nt] = __builtin_amdgcn_mfma_f32_16x16x32_bf16(af[m], bl[nt], acc[m][nt], 0, 0, 0);
              }
          }
        }
      }
    }
    // epilogue: conv-quant + identity-quant + relu -> f32 out (original NCDHW layout)
    const int h = h0 + wid;
#pragma unroll
    for (int nt = 0; nt < 4; ++nt) {
      int co = 16 * nt + r15;
      float e = e2[co];
      float sc = exp2f(7.0f - e), inv = exp2f(e - 7.0f);
      float bias = b2[co];
#pragma unroll
      for (int m = 0; m < 4; ++m)
#pragma unroll
        for (int j = 0; j < 4; ++j) {
          int w = 16 * m + 4 * g + j;
          if (w < Ww) {
            float v = acc[m][nt][j] + bias;
            float q = rintf(v * sc);
            q = fminf(fmaxf(q, -127.f), 127.f);
            v = q * inv;
            size_t xi = (((size_t)(n * Cc + co) * Tt + t) * Hh + h) * Ww + w;
            float xv = x[xi];
            float qx = rintf(xv * sc);
            qx = fminf(fmaxf(qx, -127.f), 127.f);
            out[xi] = fmaxf(qx * inv + v, 0.0f);
          }
        }
    }
}

extern "C" void kernel_launch(void* const* d_in, const int* in_sizes, int n_in,
                              void* d_out, int out_size, void* d_ws, size_t ws_size,
                              hipStream_t stream) {
    const float* x  = (const float*)d_in[0];
    const float* w1 = (const float*)d_in[1];
    const float* b1 = (const float*)d_in[2];
    const float* w2 = (const float*)d_in[3];
    const float* b2 = (const float*)d_in[4];
    const float* e1 = (const float*)d_in[5];
    const float* e2 = (const float*)d_in[6];

    // scratch layout
    const size_t NE = 25690112;            // out elems = 8*64*16*56*56
    u16* xh = (u16*)d_out;                 // d_out doubles as xh/xl scratch
    u16* xl = xh + NE;                     // exactly fills d_out (2*NE u16 = NE f32)
    char* ws = (char*)d_ws;
    u16* w1h = (u16*)(ws);
    u16* w1l = (u16*)(ws + 221184);
    u16* w2h = (u16*)(ws + 442368);
    u16* w2l = (u16*)(ws + 663552);
    u16* res1 = (u16*)(ws + 884736);       // 51.4 MB

    prep_w_kernel<<<864, 256, 0, stream>>>(w1, w2, w1h, w1l, w2h, w2l);
    split_x_kernel<<<Nn * Tt * Hh, 256, 0, stream>>>(x, xh, xl);
    const int nwg = Nn * Tt * 7;           // 896
    conv1_mfma_kernel<<<nwg, 512, 0, stream>>>(xh, xl, w1h, w1l, b1, e1, res1);
    conv2_mfma_kernel<<<nwg, 512, 0, stream>>>(res1, w2h, w2l, b2, e2, x, (float*)d_out);
}